// Round 17
// baseline (442.511 us; speedup 1.0000x reference)
//
#include <hip/hip_runtime.h>
#include <hip/hip_cooperative_groups.h>

namespace cg = cooperative_groups;

#define NN 100000
#define NE 1600000
#define IN_CH 128
#define HID_CH 64
#define OUT_CH 32
#define NB2 98               // ceil(NN/1024) coarse buckets of 1024 nodes
#define CHUNKA 8192          // edges per virtual block in bucket passes
#define NBLKA ((NE + CHUNKA - 1) / CHUNKA)   // 196
#define NBLK_GEMM ((NN + 63) / 64)           // 1563
#define NVB5 (NB2 + NBLK_GEMM)               // 1661 virtual blocks, phase 5

typedef unsigned short ushort_t;
typedef _Float16 half2_t __attribute__((ext_vector_type(2)));
typedef float f32x2 __attribute__((ext_vector_type(2)));

__device__ inline ushort_t f2bf(float f) {  // round-to-nearest-even
    union { float f; unsigned u; } v; v.f = f;
    unsigned r = v.u + 0x7fff + ((v.u >> 16) & 1);
    return (ushort_t)(r >> 16);
}
__device__ inline float blo(unsigned u) {
    union { unsigned x; float f; } v; v.x = u << 16; return v.f;
}
__device__ inline float bhi(unsigned u) {
    union { unsigned x; float f; } v; v.x = u & 0xffff0000u; return v.f;
}
__device__ inline unsigned pkh(float a, float b) {  // pack 2 f32 -> f16x2
    union { half2_t h; unsigned u; } v;
    v.h[0] = (_Float16)a; v.h[1] = (_Float16)b;
    return v.u;
}
__device__ inline half2_t u2h(unsigned u) {
    union { unsigned u; half2_t h; } v; v.u = u; return v.h;
}
__device__ inline float fdot2(unsigned a, unsigned b, float c) {
#if __has_builtin(__builtin_amdgcn_fdot2)
    return __builtin_amdgcn_fdot2(u2h(a), u2h(b), c, false);
#else
    half2_t ha = u2h(a), hb = u2h(b);
    return c + (float)ha[0] * (float)hb[0] + (float)ha[1] * (float)hb[1];
#endif
}
__device__ inline f32x2 pk_add(f32x2 a, f32x2 b) {  // v_pk_add_f32
    f32x2 r;
    asm("v_pk_add_f32 %0, %1, %2" : "=v"(r) : "v"(a), "v"(b));
    return r;
}

// Swizzle for f16-pair (uint) x-tile.
#define SWZU1(n, k2) ((n) * 64 + ((k2) ^ ((((n) & 7)) << 2)))
// Swizzle for fp32 h-tile in gemm2.
#define SWZ2(n, k) ((n) * 64 + ((k) ^ ((((n) & 7)) << 2)))

// ===== cooperative mega-kernel: CSR build + GEMM1 in one dispatch =====
__global__ __launch_bounds__(256, 4) void k_mega(
    const int* __restrict__ sa, const int* __restrict__ da,
    int* __restrict__ bhall, int* __restrict__ bbase, int* __restrict__ bcur,
    int* __restrict__ rowptr, float* __restrict__ rs,
    unsigned* __restrict__ ebuf, int* __restrict__ col,
    const float* __restrict__ x, const float* __restrict__ W1,
    const float* __restrict__ b1, ushort_t* __restrict__ xsb) {
    __shared__ int smem[8192];  // 32 KB, phase-aliased
    cg::grid_group grid = cg::this_grid();
    int t = threadIdx.x;

    // ---- phase 1: per-virtual-block bucket histogram -> bhall ----
    for (int vb = blockIdx.x; vb < NBLKA; vb += gridDim.x) {
        __syncthreads();
        for (int i = t; i < 4 * NB2; i += 256) smem[i] = 0;
        __syncthreads();
        int base = vb * CHUNKA;
        int w = t >> 6;
        for (int i = 0; i < CHUNKA; i += 256) {
            int e = base + i + t;
            if (e < NE) atomicAdd(&smem[w * NB2 + (da[e] >> 10)], 1);
        }
        __syncthreads();
        if (t < NB2)
            bhall[vb * NB2 + t] =
                smem[t] + smem[NB2 + t] + smem[2 * NB2 + t] + smem[3 * NB2 + t];
        __syncthreads();
    }
    grid.sync();

    // ---- phase 2: block 0 sums bhall columns, scans -> bbase, bcur ----
    if (blockIdx.x == 0) {
        int v = 0;
        if (t < NB2)
            for (int r = 0; r < NBLKA; ++r) v += bhall[r * NB2 + t];
        smem[t] = v;
        __syncthreads();
        for (int off = 1; off < 256; off <<= 1) {
            int xv = (t >= off) ? smem[t - off] : 0;
            __syncthreads();
            smem[t] += xv;
            __syncthreads();
        }
        int excl = smem[t] - v;
        if (t < NB2) { bbase[t] = excl; bcur[t] = excl; }
        if (t == 0) { bbase[NB2] = NE; rowptr[NN] = NE; }
    }
    grid.sync();

    // ---- phase 3: bucket fill (reuses bhall counts) -> ebuf ----
    for (int vb = blockIdx.x; vb < NBLKA; vb += gridDim.x) {
        __syncthreads();
        if (t < NB2) {
            int c = bhall[vb * NB2 + t];
            smem[t] = c ? atomicAdd(&bcur[t], c) : 0;  // lcur
        }
        __syncthreads();
        int base = vb * CHUNKA;
        for (int i = 0; i < CHUNKA; i += 256) {
            int e = base + i + t;
            if (e < NE) {
                int d = da[e];
                int p = atomicAdd(&smem[d >> 10], 1);
                ebuf[p] = ((unsigned)sa[e] << 10) | (unsigned)(d & 1023);
            }
        }
    }
    grid.sync();

    // ---- phase 4: per-bucket count + scan -> rowptr, rs ----
    // cnt = smem[0..1023], scn = smem[1024..1279]
    for (int vb = blockIdx.x; vb < NB2; vb += gridDim.x) {
        __syncthreads();
        *(int4*)&smem[t * 4] = make_int4(0, 0, 0, 0);
        __syncthreads();
        int beg = bbase[vb], end = bbase[vb + 1];
        for (int i = beg + t; i < end; i += 256)
            atomicAdd(&smem[ebuf[i] & 1023], 1);
        __syncthreads();
        int4 v4 = *(int4*)&smem[t * 4];
        int s = v4.x + v4.y + v4.z + v4.w;
        smem[1024 + t] = s;
        __syncthreads();
        for (int off = 1; off < 256; off <<= 1) {
            int xv = (t >= off) ? smem[1024 + t - off] : 0;
            __syncthreads();
            smem[1024 + t] += xv;
            __syncthreads();
        }
        int excl = smem[1024 + t] - s;
        int p0 = beg + excl;
        int p1 = p0 + v4.x;
        int p2 = p1 + v4.y;
        int p3 = p2 + v4.z;
        int n = vb * 1024 + t * 4;
        if (n + 0 < NN) { rowptr[n + 0] = p0; rs[n + 0] = rsqrtf((float)(v4.x + 1)); }
        if (n + 1 < NN) { rowptr[n + 1] = p1; rs[n + 1] = rsqrtf((float)(v4.y + 1)); }
        if (n + 2 < NN) { rowptr[n + 2] = p2; rs[n + 2] = rsqrtf((float)(v4.z + 1)); }
        if (n + 3 < NN) { rowptr[n + 3] = p3; rs[n + 3] = rsqrtf((float)(v4.w + 1)); }
    }
    grid.sync();

    // ---- phase 5: col scatter (vb < NB2) + tiled GEMM1 (vb >= NB2) ----
    unsigned* xth = (unsigned*)smem;
    unsigned* w1h = (unsigned*)smem + 4096;
    for (int vb = blockIdx.x; vb < NVB5; vb += gridDim.x) {
        __syncthreads();
        if (vb < NB2) {
            // scatter: cursors from rowptr
#pragma unroll
            for (int j = 0; j < 4; ++j) {
                int n = vb * 1024 + j * 256 + t;
                smem[j * 256 + t] = (n < NN) ? rowptr[n] : 0;
            }
            int beg = bbase[vb], end = bbase[vb + 1];
            __syncthreads();
            for (int i = beg + t; i < end; i += 256) {
                unsigned w = ebuf[i];
                int pos = atomicAdd(&smem[w & 1023], 1);
                col[pos] = (int)(w >> 10);
            }
            continue;
        }
        // tiled GEMM1 (f16 dot2)
        int base = (vb - NB2) * 64;
#pragma unroll
        for (int i = 0; i < 8; ++i) {
            int flat = i * 1024 + t * 4;
            int node = flat >> 7, k0 = flat & 127;
            int gn = base + node;
            float4 v = make_float4(0.f, 0.f, 0.f, 0.f);
            if (gn < NN) v = *(const float4*)(x + (size_t)gn * IN_CH + k0);
            uint2 pk;
            pk.x = pkh(v.x, v.y);
            pk.y = pkh(v.z, v.w);
            *(uint2*)&xth[SWZU1(node, k0 >> 1)] = pk;
        }
#pragma unroll
        for (int i = 0; i < 16; ++i) {
            int idx = i * 256 + t;
            int k2 = idx >> 6, c = idx & 63;
            float f0 = W1[(2 * k2) * 64 + c];
            float f1 = W1[(2 * k2 + 1) * 64 + c];
            w1h[idx] = pkh(f0, f1);
        }
        __syncthreads();

        int tn = t & 15, tc = t >> 4;
        int c0 = tc * 4;
        float acc[4][4];
#pragma unroll
        for (int a = 0; a < 4; ++a)
#pragma unroll
            for (int b = 0; b < 4; ++b) acc[a][b] = 0.f;

        for (int k2 = 0; k2 < 64; k2 += 2) {
            uint2 xu[4];
#pragma unroll
            for (int jn = 0; jn < 4; ++jn)
                xu[jn] = *(uint2*)&xth[SWZU1(tn + jn * 16, k2)];
            uint4 w0 = *(uint4*)&w1h[(k2 + 0) * 64 + c0];
            uint4 w1 = *(uint4*)&w1h[(k2 + 1) * 64 + c0];
            unsigned wq0[4] = {w0.x, w0.y, w0.z, w0.w};
            unsigned wq1[4] = {w1.x, w1.y, w1.z, w1.w};
#pragma unroll
            for (int jn = 0; jn < 4; ++jn)
#pragma unroll
                for (int jc = 0; jc < 4; ++jc) {
                    acc[jn][jc] = fdot2(xu[jn].x, wq0[jc], acc[jn][jc]);
                    acc[jn][jc] = fdot2(xu[jn].y, wq1[jc], acc[jn][jc]);
                }
        }

        float4 bb = *(const float4*)&b1[c0];
#pragma unroll
        for (int jn = 0; jn < 4; ++jn) {
            int gn = base + tn + jn * 16;
            if (gn < NN) {
                float r = rs[gn];
                uint2 pk;
                pk.x = (unsigned)f2bf((acc[jn][0] + bb.x) * r) |
                       ((unsigned)f2bf((acc[jn][1] + bb.y) * r) << 16);
                pk.y = (unsigned)f2bf((acc[jn][2] + bb.z) * r) |
                       ((unsigned)f2bf((acc[jn][3] + bb.w) * r) << 16);
                *(uint2*)&xsb[(size_t)gn * HID_CH + c0] = pk;
            }
        }
    }
}

// Packed accumulate of 8 bf16 channels (uint4) into 4 f32x2 via v_pk_add_f32.
#define ADD8PK(v) do { \
    f32x2 w0_, w1_, w2_, w3_; \
    w0_.x = blo((v).x); w0_.y = bhi((v).x); p0 = pk_add(p0, w0_); \
    w1_.x = blo((v).y); w1_.y = bhi((v).y); p1 = pk_add(p1, w1_); \
    w2_.x = blo((v).z); w2_.y = bhi((v).z); p2 = pk_add(p2, w2_); \
    w3_.x = blo((v).w); w3_.y = bhi((v).w); p3 = pk_add(p3, w3_); } while (0)

// ---- pull agg layer 1: wave=row, 8 groups x 8 lanes, uint4 = 8 ch ----
__global__ __launch_bounds__(256) void k_agg1(
    const int* __restrict__ rowptr, const int* __restrict__ col,
    const ushort_t* __restrict__ xsb, const float* __restrict__ rs,
    ushort_t* __restrict__ hb) {
    int gid = blockIdx.x * blockDim.x + threadIdx.x;
    int n = gid >> 6;
    if (n >= NN) return;
    int lane = threadIdx.x & 63;
    int g = lane >> 3;                       // group 0..7
    unsigned c0 = (unsigned)(lane & 7) * 8;  // channels c0..c0+7
    int beg = rowptr[n], end = rowptr[n + 1];

    f32x2 p0 = {0.f, 0.f}, p1 = {0.f, 0.f}, p2 = {0.f, 0.f}, p3 = {0.f, 0.f};
    if (g == 0) {  // self-loop
        uint4 sv = *(const uint4*)&xsb[(unsigned)n * 64u + c0];
        ADD8PK(sv);
    }

    int i = beg;
    for (; i + 16 <= end; i += 16) {  // 16 edges/iter (2 per group)
        int s0 = col[i + g];
        int s1 = col[i + 8 + g];
        uint4 v0 = *(const uint4*)&xsb[(unsigned)s0 * 64u + c0];
        uint4 v1 = *(const uint4*)&xsb[(unsigned)s1 * 64u + c0];
        ADD8PK(v0);
        ADD8PK(v1);
    }
    if (i + 8 <= end) {
        int s0 = col[i + g];
        uint4 v0 = *(const uint4*)&xsb[(unsigned)s0 * 64u + c0];
        ADD8PK(v0);
        i += 8;
    }
    int r = end - i;  // 0..7
    if (g < r) {
        int s0 = col[i + g];
        uint4 v0 = *(const uint4*)&xsb[(unsigned)s0 * 64u + c0];
        ADD8PK(v0);
    }

    float a0 = p0.x, a1 = p0.y, a2 = p1.x, a3 = p1.y;
    float a4 = p2.x, a5 = p2.y, a6 = p3.x, a7 = p3.y;
#pragma unroll
    for (int m = 8; m <= 32; m <<= 1) {
        a0 += __shfl_xor(a0, m); a1 += __shfl_xor(a1, m);
        a2 += __shfl_xor(a2, m); a3 += __shfl_xor(a3, m);
        a4 += __shfl_xor(a4, m); a5 += __shfl_xor(a5, m);
        a6 += __shfl_xor(a6, m); a7 += __shfl_xor(a7, m);
    }

    if (g == 0) {
        float rn = rs[n];
        uint4 pk;
        pk.x = (unsigned)f2bf(fmaxf(a0 * rn, 0.f)) |
               ((unsigned)f2bf(fmaxf(a1 * rn, 0.f)) << 16);
        pk.y = (unsigned)f2bf(fmaxf(a2 * rn, 0.f)) |
               ((unsigned)f2bf(fmaxf(a3 * rn, 0.f)) << 16);
        pk.z = (unsigned)f2bf(fmaxf(a4 * rn, 0.f)) |
               ((unsigned)f2bf(fmaxf(a5 * rn, 0.f)) << 16);
        pk.w = (unsigned)f2bf(fmaxf(a6 * rn, 0.f)) |
               ((unsigned)f2bf(fmaxf(a7 * rn, 0.f)) << 16);
        *(uint4*)&hb[(unsigned)n * 64u + c0] = pk;
    }
}

// ---- tiled GEMM2: ysb[n][c] = bf16(((h[n] @ W2 + b2)[c]) * rs[n]) ----
__global__ __launch_bounds__(256) void k_gemm2(
    const ushort_t* __restrict__ hb, const float* __restrict__ W2,
    const float* __restrict__ b2, const float* __restrict__ rs,
    ushort_t* __restrict__ ysb) {
    __shared__ float ht[64 * 64];   // 16 KB, swizzled fp32
    __shared__ float w2s[64 * 32];  // 8 KB
    int t = threadIdx.x;
    int base = blockIdx.x * 64;

#pragma unroll
    for (int i = 0; i < 8; ++i) {
        int uidx = i * 256 + t;            // 2048 uints total
        int node = uidx >> 5, k2 = uidx & 31;
        int gn = base + node;
        unsigned u = 0;
        if (gn < NN) u = *(const unsigned*)&hb[(size_t)gn * HID_CH + k2 * 2];
        float2 f; f.x = blo(u); f.y = bhi(u);
        *(float2*)&ht[SWZ2(node, k2 * 2)] = f;
    }
#pragma unroll
    for (int i = 0; i < 2; ++i) {
        int flat = i * 1024 + t * 4;
        *(float4*)&w2s[flat] = *(const float4*)(W2 + flat);
    }
    __syncthreads();

    int tn = t & 15, tc = t >> 4;
    int c0 = tc * 2;
    float acc[4][2];
#pragma unroll
    for (int a = 0; a < 4; ++a) { acc[a][0] = 0.f; acc[a][1] = 0.f; }

    for (int k0 = 0; k0 < 64; k0 += 4) {
        float xq[4][4], wq[4][2];
#pragma unroll
        for (int j = 0; j < 4; ++j)
            *(float2*)&wq[j][0] = *(float2*)&w2s[(k0 + j) * 32 + c0];
#pragma unroll
        for (int jn = 0; jn < 4; ++jn)
            *(float4*)&xq[jn][0] = *(float4*)&ht[SWZ2(tn + jn * 16, k0)];
#pragma unroll
        for (int jn = 0; jn < 4; ++jn)
#pragma unroll
            for (int j = 0; j < 4; ++j) {
                acc[jn][0] = fmaf(xq[jn][j], wq[j][0], acc[jn][0]);
                acc[jn][1] = fmaf(xq[jn][j], wq[j][1], acc[jn][1]);
            }
    }

    float2 bb = *(const float2*)&b2[c0];
#pragma unroll
    for (int jn = 0; jn < 4; ++jn) {
        int gn = base + tn + jn * 16;
        if (gn < NN) {
            float r = rs[gn];
            unsigned pk = (unsigned)f2bf((acc[jn][0] + bb.x) * r) |
                          ((unsigned)f2bf((acc[jn][1] + bb.y) * r) << 16);
            *(unsigned*)&ysb[(size_t)gn * OUT_CH + c0] = pk;
        }
    }
}

// ---- pull agg layer 2: wave=row, 16 groups x 4 lanes, uint4 = 8 ch ----
__global__ __launch_bounds__(256) void k_agg2(
    const int* __restrict__ rowptr, const int* __restrict__ col,
    const ushort_t* __restrict__ ysb, const float* __restrict__ rs,
    float* __restrict__ out) {
    int gid = blockIdx.x * blockDim.x + threadIdx.x;
    int n = gid >> 6;
    if (n >= NN) return;
    int lane = threadIdx.x & 63;
    int g = lane >> 2;                       // group 0..15
    unsigned c0 = (unsigned)(lane & 3) * 8;  // channels c0..c0+7
    int beg = rowptr[n], end = rowptr[n + 1];

    f32x2 p0 = {0.f, 0.f}, p1 = {0.f, 0.f}, p2 = {0.f, 0.f}, p3 = {0.f, 0.f};
    if (g == 0) {  // self-loop
        uint4 sv = *(const uint4*)&ysb[(unsigned)n * 32u + c0];
        ADD8PK(sv);
    }

    int i = beg;
    for (; i + 16 <= end; i += 16) {  // 16 edges/iter (1 per group)
        int s0 = col[i + g];
        uint4 v0 = *(const uint4*)&ysb[(unsigned)s0 * 32u + c0];
        ADD8PK(v0);
    }
    int r = end - i;  // 0..15
    if (g < r) {
        int s0 = col[i + g];
        uint4 v0 = *(const uint4*)&ysb[(unsigned)s0 * 32u + c0];
        ADD8PK(v0);
    }

    float a0 = p0.x, a1 = p0.y, a2 = p1.x, a3 = p1.y;
    float a4 = p2.x, a5 = p2.y, a6 = p3.x, a7 = p3.y;
#pragma unroll
    for (int m = 4; m <= 32; m <<= 1) {
        a0 += __shfl_xor(a0, m); a1 += __shfl_xor(a1, m);
        a2 += __shfl_xor(a2, m); a3 += __shfl_xor(a3, m);
        a4 += __shfl_xor(a4, m); a5 += __shfl_xor(a5, m);
        a6 += __shfl_xor(a6, m); a7 += __shfl_xor(a7, m);
    }

    if (g == 0) {
        float rn = rs[n];
        float4 o0, o1;
        o0.x = a0 * rn; o0.y = a1 * rn; o0.z = a2 * rn; o0.w = a3 * rn;
        o1.x = a4 * rn; o1.y = a5 * rn; o1.z = a6 * rn; o1.w = a7 * rn;
        *(float4*)&out[(size_t)n * OUT_CH + c0] = o0;
        *(float4*)&out[(size_t)n * OUT_CH + c0 + 4] = o1;
    }
}

extern "C" void kernel_launch(void* const* d_in, const int* in_sizes, int n_in,
                              void* d_out, int out_size, void* d_ws, size_t ws_size,
                              hipStream_t stream) {
    const float* x  = (const float*)d_in[0];
    const int*   ei = (const int*)d_in[1];  // (2, E): row 0 = src, row 1 = dst
    const float* W1 = (const float*)d_in[2];
    const float* b1 = (const float*)d_in[3];
    const float* W2 = (const float*)d_in[4];
    const float* b2 = (const float*)d_in[5];
    const int* sa = ei;
    const int* da = ei + NE;

    char* ws = (char*)d_ws;
    size_t off = 0;
    auto alloc = [&](size_t bytes) {
        void* p = ws + off;
        off += (bytes + 255) & ~(size_t)255;
        return p;
    };
    int*      bbase  = (int*)alloc((size_t)(NB2 + 1) * 4);
    int*      bcur   = (int*)alloc((size_t)NB2 * 4);
    int*      bhall  = (int*)alloc((size_t)NBLKA * NB2 * 4);  // 77 KB
    int*      rowptr = (int*)alloc((size_t)(NN + 1) * 4);
    float*    rs     = (float*)alloc((size_t)NN * 4);
    unsigned* ebuf   = (unsigned*)alloc((size_t)NE * 4);
    int*      col    = (int*)alloc((size_t)NE * 4);
    ushort_t* xsb    = (ushort_t*)alloc((size_t)NN * HID_CH * 2);  // 12.8 MB
    ushort_t* hb     = (ushort_t*)alloc((size_t)NN * HID_CH * 2);  // 12.8 MB
    ushort_t* ysb    = (ushort_t*)alloc((size_t)NN * OUT_CH * 2);  // 6.4 MB
    float*    outp   = (float*)d_out;

    const int B = 256;

    // cooperative grid: cap at co-resident capacity
    int maxBlocksPerCU = 0;
    hipOccupancyMaxActiveBlocksPerMultiprocessor(&maxBlocksPerCU, k_mega, 256, 0);
    if (maxBlocksPerCU < 1) maxBlocksPerCU = 1;
    int nbg = maxBlocksPerCU * 256;  // 256 CUs on MI355X
    if (nbg > NVB5) nbg = NVB5;

    void* args[] = {(void*)&sa, (void*)&da, (void*)&bhall, (void*)&bbase,
                    (void*)&bcur, (void*)&rowptr, (void*)&rs, (void*)&ebuf,
                    (void*)&col, (void*)&x, (void*)&W1, (void*)&b1, (void*)&xsb};
    hipLaunchCooperativeKernel((void*)k_mega, dim3(nbg), dim3(256), args, 0, stream);

    k_agg1<<<(NN * 64 + B - 1) / B, B, 0, stream>>>(rowptr, col, xsb, rs, hb);
    k_gemm2<<<NBLK_GEMM, 256, 0, stream>>>(hb, W2, b2, rs, ysb);
    k_agg2<<<(NN * 64 + B - 1) / B, B, 0, stream>>>(rowptr, col, ysb, rs, outp);
}

// Round 18
// 353.485 us; speedup vs baseline: 1.2519x; 1.2519x over previous
//
#include <hip/hip_runtime.h>

#define NN 100000
#define NE 1600000
#define IN_CH 128
#define HID_CH 64
#define OUT_CH 32
#define NB2 98               // ceil(NN/1024) coarse buckets of 1024 nodes
#define CHUNKA 8192          // edges per block in bucket passes
#define NBLKA ((NE + CHUNKA - 1) / CHUNKA)   // 196
#define NBLK_GEMM ((NN + 63) / 64)           // 1563
#define HPAD 68              // padded h-row stride (floats): 16B-aligned, ~2-way banks

typedef unsigned short ushort_t;
typedef _Float16 half2_t __attribute__((ext_vector_type(2)));
typedef float f32x2 __attribute__((ext_vector_type(2)));

__device__ inline ushort_t f2bf(float f) {  // round-to-nearest-even
    union { float f; unsigned u; } v; v.f = f;
    unsigned r = v.u + 0x7fff + ((v.u >> 16) & 1);
    return (ushort_t)(r >> 16);
}
__device__ inline float blo(unsigned u) {
    union { unsigned x; float f; } v; v.x = u << 16; return v.f;
}
__device__ inline float bhi(unsigned u) {
    union { unsigned x; float f; } v; v.x = u & 0xffff0000u; return v.f;
}
__device__ inline unsigned pkh(float a, float b) {  // pack 2 f32 -> f16x2
    union { half2_t h; unsigned u; } v;
    v.h[0] = (_Float16)a; v.h[1] = (_Float16)b;
    return v.u;
}
__device__ inline half2_t u2h(unsigned u) {
    union { unsigned u; half2_t h; } v; v.u = u; return v.h;
}
__device__ inline float fdot2(unsigned a, unsigned b, float c) {
#if __has_builtin(__builtin_amdgcn_fdot2)
    return __builtin_amdgcn_fdot2(u2h(a), u2h(b), c, false);
#else
    half2_t ha = u2h(a), hb = u2h(b);
    return c + (float)ha[0] * (float)hb[0] + (float)ha[1] * (float)hb[1];
#endif
}
__device__ inline f32x2 pk_add(f32x2 a, f32x2 b) {  // v_pk_add_f32
    f32x2 r;
    asm("v_pk_add_f32 %0, %1, %2" : "=v"(r) : "v"(a), "v"(b));
    return r;
}

// ---- coarse bucket histogram (dst>>10); per-block rows only ----
__global__ __launch_bounds__(256) void k_bhist(const int* __restrict__ da,
                                               int* __restrict__ bhall) {
    __shared__ int hist[4][NB2];
    int t = threadIdx.x, w = t >> 6;
    for (int i = t; i < 4 * NB2; i += 256) ((int*)hist)[i] = 0;
    __syncthreads();
    int base = blockIdx.x * CHUNKA;
    for (int i = 0; i < CHUNKA; i += 256) {
        int e = base + i + t;
        if (e < NE) atomicAdd(&hist[w][da[e] >> 10], 1);
    }
    __syncthreads();
    if (t < NB2)
        bhall[blockIdx.x * NB2 + t] =
            hist[0][t] + hist[1][t] + hist[2][t] + hist[3][t];
}

// ---- scan: column-sum bhall -> counts, then exclusive scan (one block) ----
__global__ __launch_bounds__(128) void k_bscan(const int* __restrict__ bhall,
                                               int* __restrict__ bbase,
                                               int* __restrict__ bcur,
                                               int* __restrict__ rowptr) {
    __shared__ int lds[128];
    int t = threadIdx.x;
    int v = 0;
    if (t < NB2)
        for (int r = 0; r < NBLKA; ++r) v += bhall[r * NB2 + t];
    lds[t] = v;
    __syncthreads();
    for (int off = 1; off < 128; off <<= 1) {
        int x = (t >= off) ? lds[t - off] : 0;
        __syncthreads();
        lds[t] += x;
        __syncthreads();
    }
    int excl = lds[t] - v;
    if (t < NB2) { bbase[t] = excl; bcur[t] = excl; }
    if (t == 0) { bbase[NB2] = NE; rowptr[NN] = NE; }
}

// ---- bucket fill: reuses bhist's stored counts (no recount pass) ----
__global__ __launch_bounds__(256) void k_bfill(const int* __restrict__ sa,
                                               const int* __restrict__ da,
                                               const int* __restrict__ bhall,
                                               int* __restrict__ bcur,
                                               unsigned* __restrict__ ebuf) {
    __shared__ int lcur[NB2];
    int t = threadIdx.x;
    if (t < NB2) {
        int c = bhall[blockIdx.x * NB2 + t];
        lcur[t] = c ? atomicAdd(&bcur[t], c) : 0;
    }
    __syncthreads();
    int base = blockIdx.x * CHUNKA;
    for (int i = 0; i < CHUNKA; i += 256) {
        int e = base + i + t;
        if (e < NE) {
            int d = da[e];
            int p = atomicAdd(&lcur[d >> 10], 1);
            ebuf[p] = ((unsigned)sa[e] << 10) | (unsigned)(d & 1023);
        }
    }
}

// ---- count pass: per-bucket node counts -> rowptr, rs (NO scatter) ----
__global__ __launch_bounds__(1024) void k_bcount(const unsigned* __restrict__ ebuf,
                                                 const int* __restrict__ bbase,
                                                 int* __restrict__ rowptr,
                                                 float* __restrict__ rs) {
    __shared__ int cnt[1024];
    __shared__ int scn[1024];
    int b = blockIdx.x, t = threadIdx.x;
    int nb = NN - b * 1024; if (nb > 1024) nb = 1024;
    int beg = bbase[b], end = bbase[b + 1];
    cnt[t] = 0;
    __syncthreads();
    for (int i = beg + t; i < end; i += 1024) atomicAdd(&cnt[ebuf[i] & 1023], 1);
    __syncthreads();
    int v = cnt[t];
    scn[t] = v;
    __syncthreads();
    for (int off = 1; off < 1024; off <<= 1) {
        int x = (t >= off) ? scn[t - off] : 0;
        __syncthreads();
        scn[t] += x;
        __syncthreads();
    }
    int excl = scn[t] - v;
    if (t < nb) {
        rowptr[b * 1024 + t] = beg + excl;
        rs[b * 1024 + t] = rsqrtf((float)(v + 1));
    }
}

// Swizzle for f16-pair (uint) x-tile.
#define SWZU1(n, k2) ((n) * 64 + ((k2) ^ ((((n) & 7)) << 2)))

// ---- FUSED: blocks 0..NB2-1 scatter col (cursors from rowptr);
//      blocks NB2.. run tiled GEMM1 (f16 dot2). ----
__global__ __launch_bounds__(256, 4) void k_scatter_gemm1(
    const unsigned* __restrict__ ebuf, const int* __restrict__ rowptr,
    const int* __restrict__ bbase, int* __restrict__ col,
    const float* __restrict__ x, const float* __restrict__ W1,
    const float* __restrict__ b1, const float* __restrict__ rs,
    ushort_t* __restrict__ xsb) {
    __shared__ unsigned xth[64 * 64];  // 16 KB (gemm1 path)
    __shared__ unsigned w1h[64 * 64];  // 16 KB (gemm1 path)
    __shared__ int cur[1024];          // 4 KB (scatter path)
    int t = threadIdx.x;

    if (blockIdx.x < NB2) {
        int b = blockIdx.x;
#pragma unroll
        for (int j = 0; j < 4; ++j) {
            int n = b * 1024 + j * 256 + t;
            cur[j * 256 + t] = (n < NN) ? rowptr[n] : 0;
        }
        int beg = bbase[b], end = bbase[b + 1];
        __syncthreads();
        for (int i = beg + t; i < end; i += 256) {
            unsigned w = ebuf[i];
            int pos = atomicAdd(&cur[w & 1023], 1);
            col[pos] = (int)(w >> 10);
        }
        return;
    }

    int base = (blockIdx.x - NB2) * 64;
#pragma unroll
    for (int i = 0; i < 8; ++i) {
        int flat = i * 1024 + t * 4;
        int node = flat >> 7, k0 = flat & 127;
        int gn = base + node;
        float4 v = make_float4(0.f, 0.f, 0.f, 0.f);
        if (gn < NN) v = *(const float4*)(x + (size_t)gn * IN_CH + k0);
        uint2 pk;
        pk.x = pkh(v.x, v.y);
        pk.y = pkh(v.z, v.w);
        *(uint2*)&xth[SWZU1(node, k0 >> 1)] = pk;
    }
#pragma unroll
    for (int i = 0; i < 16; ++i) {
        int idx = i * 256 + t;
        int k2 = idx >> 6, c = idx & 63;
        float f0 = W1[(2 * k2) * 64 + c];
        float f1 = W1[(2 * k2 + 1) * 64 + c];
        w1h[idx] = pkh(f0, f1);
    }
    __syncthreads();

    int tn = t & 15, tc = t >> 4;
    int c0 = tc * 4;
    float acc[4][4];
#pragma unroll
    for (int a = 0; a < 4; ++a)
#pragma unroll
        for (int b = 0; b < 4; ++b) acc[a][b] = 0.f;

    for (int k2 = 0; k2 < 64; k2 += 2) {
        uint2 xu[4];
#pragma unroll
        for (int jn = 0; jn < 4; ++jn)
            xu[jn] = *(uint2*)&xth[SWZU1(tn + jn * 16, k2)];
        uint4 w0 = *(uint4*)&w1h[(k2 + 0) * 64 + c0];
        uint4 w1 = *(uint4*)&w1h[(k2 + 1) * 64 + c0];
        unsigned wq0[4] = {w0.x, w0.y, w0.z, w0.w};
        unsigned wq1[4] = {w1.x, w1.y, w1.z, w1.w};
#pragma unroll
        for (int jn = 0; jn < 4; ++jn)
#pragma unroll
            for (int jc = 0; jc < 4; ++jc) {
                acc[jn][jc] = fdot2(xu[jn].x, wq0[jc], acc[jn][jc]);
                acc[jn][jc] = fdot2(xu[jn].y, wq1[jc], acc[jn][jc]);
            }
    }

    float4 bb = *(const float4*)&b1[c0];
#pragma unroll
    for (int jn = 0; jn < 4; ++jn) {
        int gn = base + tn + jn * 16;
        if (gn < NN) {
            float r = rs[gn];
            uint2 pk;
            pk.x = (unsigned)f2bf((acc[jn][0] + bb.x) * r) |
                   ((unsigned)f2bf((acc[jn][1] + bb.y) * r) << 16);
            pk.y = (unsigned)f2bf((acc[jn][2] + bb.z) * r) |
                   ((unsigned)f2bf((acc[jn][3] + bb.w) * r) << 16);
            *(uint2*)&xsb[(size_t)gn * HID_CH + c0] = pk;
        }
    }
}

// Packed accumulate of 8 bf16 channels (uint4) into 4 f32x2 via v_pk_add_f32.
#define ADD8PK(v) do { \
    f32x2 w0_, w1_, w2_, w3_; \
    w0_.x = blo((v).x); w0_.y = bhi((v).x); p0 = pk_add(p0, w0_); \
    w1_.x = blo((v).y); w1_.y = bhi((v).y); p1 = pk_add(p1, w1_); \
    w2_.x = blo((v).z); w2_.y = bhi((v).z); p2 = pk_add(p2, w2_); \
    w3_.x = blo((v).w); w3_.y = bhi((v).w); p3 = pk_add(p3, w3_); } while (0)

// ---- FUSED agg layer 1 + tiled GEMM2: block = 64 dst rows.
// Phase A: 4 waves x 16 rows, gather (8 groups x 8 lanes, uint4), h -> LDS.
// Phase B: tiled GEMM2 from LDS h -> ysb. ----
__global__ __launch_bounds__(256) void k_agg1g2(
    const int* __restrict__ rowptr, const int* __restrict__ col,
    const ushort_t* __restrict__ xsb, const float* __restrict__ rs,
    const float* __restrict__ W2, const float* __restrict__ b2,
    ushort_t* __restrict__ ysb) {
    __shared__ float ht[64 * HPAD];   // 17.4 KB padded h tile
    __shared__ float w2s[64 * 32];    // 8 KB
    int t = threadIdx.x;
    int base = blockIdx.x * 64;

    // preload W2 while gathers will be in flight
#pragma unroll
    for (int i = 0; i < 2; ++i) {
        int flat = i * 1024 + t * 4;
        *(float4*)&w2s[flat] = *(const float4*)(W2 + flat);
    }

    int wv = t >> 6;                         // wave 0..3
    int lane = t & 63;
    int g = lane >> 3;                       // group 0..7
    unsigned c0 = (unsigned)(lane & 7) * 8;  // channels c0..c0+7

    // ---- phase A: gather 16 rows per wave ----
    for (int j = 0; j < 16; ++j) {
        int nl = wv * 16 + j;
        int n = base + nl;
        if (n >= NN) break;
        int beg = rowptr[n], end = rowptr[n + 1];

        f32x2 p0 = {0.f, 0.f}, p1 = {0.f, 0.f}, p2 = {0.f, 0.f}, p3 = {0.f, 0.f};
        if (g == 0) {  // self-loop
            uint4 sv = *(const uint4*)&xsb[(unsigned)n * 64u + c0];
            ADD8PK(sv);
        }

        int i = beg;
        for (; i + 16 <= end; i += 16) {
            int s0 = col[i + g];
            int s1 = col[i + 8 + g];
            uint4 v0 = *(const uint4*)&xsb[(unsigned)s0 * 64u + c0];
            uint4 v1 = *(const uint4*)&xsb[(unsigned)s1 * 64u + c0];
            ADD8PK(v0);
            ADD8PK(v1);
        }
        if (i + 8 <= end) {
            int s0 = col[i + g];
            uint4 v0 = *(const uint4*)&xsb[(unsigned)s0 * 64u + c0];
            ADD8PK(v0);
            i += 8;
        }
        int r = end - i;  // 0..7
        if (g < r) {
            int s0 = col[i + g];
            uint4 v0 = *(const uint4*)&xsb[(unsigned)s0 * 64u + c0];
            ADD8PK(v0);
        }

        float a0 = p0.x, a1 = p0.y, a2 = p1.x, a3 = p1.y;
        float a4 = p2.x, a5 = p2.y, a6 = p3.x, a7 = p3.y;
#pragma unroll
        for (int m = 8; m <= 32; m <<= 1) {
            a0 += __shfl_xor(a0, m); a1 += __shfl_xor(a1, m);
            a2 += __shfl_xor(a2, m); a3 += __shfl_xor(a3, m);
            a4 += __shfl_xor(a4, m); a5 += __shfl_xor(a5, m);
            a6 += __shfl_xor(a6, m); a7 += __shfl_xor(a7, m);
        }

        if (g == 0) {
            float rn = rs[n];
            float4 h0, h1;
            h0.x = fmaxf(a0 * rn, 0.f); h0.y = fmaxf(a1 * rn, 0.f);
            h0.z = fmaxf(a2 * rn, 0.f); h0.w = fmaxf(a3 * rn, 0.f);
            h1.x = fmaxf(a4 * rn, 0.f); h1.y = fmaxf(a5 * rn, 0.f);
            h1.z = fmaxf(a6 * rn, 0.f); h1.w = fmaxf(a7 * rn, 0.f);
            *(float4*)&ht[nl * HPAD + c0] = h0;
            *(float4*)&ht[nl * HPAD + c0 + 4] = h1;
        }
    }
    __syncthreads();

    // ---- phase B: tiled GEMM2 from LDS h ----
    int tn = t & 15, tc = t >> 4;
    int cc0 = tc * 2;
    float acc[4][2];
#pragma unroll
    for (int a = 0; a < 4; ++a) { acc[a][0] = 0.f; acc[a][1] = 0.f; }

    for (int k0 = 0; k0 < 64; k0 += 4) {
        float xq[4][4], wq[4][2];
#pragma unroll
        for (int j = 0; j < 4; ++j)
            *(float2*)&wq[j][0] = *(float2*)&w2s[(k0 + j) * 32 + cc0];
#pragma unroll
        for (int jn = 0; jn < 4; ++jn)
            *(float4*)&xq[jn][0] = *(float4*)&ht[(tn + jn * 16) * HPAD + k0];
#pragma unroll
        for (int jn = 0; jn < 4; ++jn)
#pragma unroll
            for (int j = 0; j < 4; ++j) {
                acc[jn][0] = fmaf(xq[jn][j], wq[j][0], acc[jn][0]);
                acc[jn][1] = fmaf(xq[jn][j], wq[j][1], acc[jn][1]);
            }
    }

    float2 bb = *(const float2*)&b2[cc0];
#pragma unroll
    for (int jn = 0; jn < 4; ++jn) {
        int gn = base + tn + jn * 16;
        if (gn < NN) {
            float r = rs[gn];
            unsigned pk = (unsigned)f2bf((acc[jn][0] + bb.x) * r) |
                          ((unsigned)f2bf((acc[jn][1] + bb.y) * r) << 16);
            *(unsigned*)&ysb[(size_t)gn * OUT_CH + cc0] = pk;
        }
    }
}

// ---- pull agg layer 2: wave=row, 16 groups x 4 lanes, uint4 = 8 ch ----
__global__ __launch_bounds__(256) void k_agg2(
    const int* __restrict__ rowptr, const int* __restrict__ col,
    const ushort_t* __restrict__ ysb, const float* __restrict__ rs,
    float* __restrict__ out) {
    int gid = blockIdx.x * blockDim.x + threadIdx.x;
    int n = gid >> 6;
    if (n >= NN) return;
    int lane = threadIdx.x & 63;
    int g = lane >> 2;                       // group 0..15
    unsigned c0 = (unsigned)(lane & 3) * 8;  // channels c0..c0+7
    int beg = rowptr[n], end = rowptr[n + 1];

    f32x2 p0 = {0.f, 0.f}, p1 = {0.f, 0.f}, p2 = {0.f, 0.f}, p3 = {0.f, 0.f};
    if (g == 0) {  // self-loop
        uint4 sv = *(const uint4*)&ysb[(unsigned)n * 32u + c0];
        ADD8PK(sv);
    }

    int i = beg;
    for (; i + 16 <= end; i += 16) {  // 16 edges/iter (1 per group)
        int s0 = col[i + g];
        uint4 v0 = *(const uint4*)&ysb[(unsigned)s0 * 32u + c0];
        ADD8PK(v0);
    }
    int r = end - i;  // 0..15
    if (g < r) {
        int s0 = col[i + g];
        uint4 v0 = *(const uint4*)&ysb[(unsigned)s0 * 32u + c0];
        ADD8PK(v0);
    }

    float a0 = p0.x, a1 = p0.y, a2 = p1.x, a3 = p1.y;
    float a4 = p2.x, a5 = p2.y, a6 = p3.x, a7 = p3.y;
#pragma unroll
    for (int m = 4; m <= 32; m <<= 1) {
        a0 += __shfl_xor(a0, m); a1 += __shfl_xor(a1, m);
        a2 += __shfl_xor(a2, m); a3 += __shfl_xor(a3, m);
        a4 += __shfl_xor(a4, m); a5 += __shfl_xor(a5, m);
        a6 += __shfl_xor(a6, m); a7 += __shfl_xor(a7, m);
    }

    if (g == 0) {
        float rn = rs[n];
        float4 o0, o1;
        o0.x = a0 * rn; o0.y = a1 * rn; o0.z = a2 * rn; o0.w = a3 * rn;
        o1.x = a4 * rn; o1.y = a5 * rn; o1.z = a6 * rn; o1.w = a7 * rn;
        *(float4*)&out[(size_t)n * OUT_CH + c0] = o0;
        *(float4*)&out[(size_t)n * OUT_CH + c0 + 4] = o1;
    }
}

extern "C" void kernel_launch(void* const* d_in, const int* in_sizes, int n_in,
                              void* d_out, int out_size, void* d_ws, size_t ws_size,
                              hipStream_t stream) {
    const float* x  = (const float*)d_in[0];
    const int*   ei = (const int*)d_in[1];  // (2, E): row 0 = src, row 1 = dst
    const float* W1 = (const float*)d_in[2];
    const float* b1 = (const float*)d_in[3];
    const float* W2 = (const float*)d_in[4];
    const float* b2 = (const float*)d_in[5];
    const int* sa = ei;
    const int* da = ei + NE;

    char* ws = (char*)d_ws;
    size_t off = 0;
    auto alloc = [&](size_t bytes) {
        void* p = ws + off;
        off += (bytes + 255) & ~(size_t)255;
        return p;
    };
    int*      bbase  = (int*)alloc((size_t)(NB2 + 1) * 4);
    int*      bcur   = (int*)alloc((size_t)NB2 * 4);
    int*      bhall  = (int*)alloc((size_t)NBLKA * NB2 * 4);  // 77 KB
    int*      rowptr = (int*)alloc((size_t)(NN + 1) * 4);
    float*    rs     = (float*)alloc((size_t)NN * 4);
    unsigned* ebuf   = (unsigned*)alloc((size_t)NE * 4);
    int*      col    = (int*)alloc((size_t)NE * 4);
    ushort_t* xsb    = (ushort_t*)alloc((size_t)NN * HID_CH * 2);  // 12.8 MB
    ushort_t* ysb    = (ushort_t*)alloc((size_t)NN * OUT_CH * 2);  // 6.4 MB
    float*    outp   = (float*)d_out;

    const int B = 256;
    k_bhist<<<NBLKA, 256, 0, stream>>>(da, bhall);
    k_bscan<<<1, 128, 0, stream>>>(bhall, bbase, bcur, rowptr);
    k_bfill<<<NBLKA, 256, 0, stream>>>(sa, da, bhall, bcur, ebuf);
    k_bcount<<<NB2, 1024, 0, stream>>>(ebuf, bbase, rowptr, rs);
    k_scatter_gemm1<<<NB2 + NBLK_GEMM, 256, 0, stream>>>(ebuf, rowptr, bbase, col,
                                                         x, W1, b1, rs, xsb);
    k_agg1g2<<<NBLK_GEMM, 256, 0, stream>>>(rowptr, col, xsb, rs, W2, b2, ysb);
    k_agg2<<<(NN * 64 + B - 1) / B, B, 0, stream>>>(rowptr, col, ysb, rs, outp);
}

// Round 19
// 217.845 us; speedup vs baseline: 2.0313x; 1.6226x over previous
//
#include <hip/hip_runtime.h>

#define NN 100000
#define NE 1600000
#define IN_CH 128
#define HID_CH 64
#define OUT_CH 32
#define NB2 98               // ceil(NN/1024) coarse buckets of 1024 nodes
#define CHUNKA 8192          // edges per block in bucket passes
#define NBLKA ((NE + CHUNKA - 1) / CHUNKA)   // 196
#define NBLK_GEMM ((NN + 63) / 64)           // 1563

typedef unsigned short ushort_t;
typedef _Float16 half2_t __attribute__((ext_vector_type(2)));
typedef float f32x2 __attribute__((ext_vector_type(2)));

__device__ inline ushort_t f2bf(float f) {  // round-to-nearest-even
    union { float f; unsigned u; } v; v.f = f;
    unsigned r = v.u + 0x7fff + ((v.u >> 16) & 1);
    return (ushort_t)(r >> 16);
}
__device__ inline float blo(unsigned u) {
    union { unsigned x; float f; } v; v.x = u << 16; return v.f;
}
__device__ inline float bhi(unsigned u) {
    union { unsigned x; float f; } v; v.x = u & 0xffff0000u; return v.f;
}
__device__ inline unsigned pkh(float a, float b) {  // pack 2 f32 -> f16x2
    union { half2_t h; unsigned u; } v;
    v.h[0] = (_Float16)a; v.h[1] = (_Float16)b;
    return v.u;
}
__device__ inline half2_t u2h(unsigned u) {
    union { unsigned u; half2_t h; } v; v.u = u; return v.h;
}
__device__ inline float fdot2(unsigned a, unsigned b, float c) {
#if __has_builtin(__builtin_amdgcn_fdot2)
    return __builtin_amdgcn_fdot2(u2h(a), u2h(b), c, false);
#else
    half2_t ha = u2h(a), hb = u2h(b);
    return c + (float)ha[0] * (float)hb[0] + (float)ha[1] * (float)hb[1];
#endif
}
__device__ inline f32x2 pk_add(f32x2 a, f32x2 b) {  // v_pk_add_f32
    f32x2 r;
    asm("v_pk_add_f32 %0, %1, %2" : "=v"(r) : "v"(a), "v"(b));
    return r;
}

// ---- coarse bucket histogram (dst>>10); per-block rows only ----
__global__ __launch_bounds__(256) void k_bhist(const int* __restrict__ da,
                                               int* __restrict__ bhall) {
    __shared__ int hist[4][NB2];
    int t = threadIdx.x, w = t >> 6;
    for (int i = t; i < 4 * NB2; i += 256) ((int*)hist)[i] = 0;
    __syncthreads();
    int base = blockIdx.x * CHUNKA;
    for (int i = 0; i < CHUNKA; i += 256) {
        int e = base + i + t;
        if (e < NE) atomicAdd(&hist[w][da[e] >> 10], 1);
    }
    __syncthreads();
    if (t < NB2)
        bhall[blockIdx.x * NB2 + t] =
            hist[0][t] + hist[1][t] + hist[2][t] + hist[3][t];
}

// ---- scan: column-sum bhall -> counts, then exclusive scan (one block) ----
__global__ __launch_bounds__(128) void k_bscan(const int* __restrict__ bhall,
                                               int* __restrict__ bbase,
                                               int* __restrict__ bcur,
                                               int* __restrict__ rowptr) {
    __shared__ int lds[128];
    int t = threadIdx.x;
    int v = 0;
    if (t < NB2)
        for (int r = 0; r < NBLKA; ++r) v += bhall[r * NB2 + t];
    lds[t] = v;
    __syncthreads();
    for (int off = 1; off < 128; off <<= 1) {
        int x = (t >= off) ? lds[t - off] : 0;
        __syncthreads();
        lds[t] += x;
        __syncthreads();
    }
    int excl = lds[t] - v;
    if (t < NB2) { bbase[t] = excl; bcur[t] = excl; }
    if (t == 0) { bbase[NB2] = NE; rowptr[NN] = NE; }
}

// ---- bucket fill: reuses bhist's stored counts (no recount pass) ----
__global__ __launch_bounds__(256) void k_bfill(const int* __restrict__ sa,
                                               const int* __restrict__ da,
                                               const int* __restrict__ bhall,
                                               int* __restrict__ bcur,
                                               unsigned* __restrict__ ebuf) {
    __shared__ int lcur[NB2];
    int t = threadIdx.x;
    if (t < NB2) {
        int c = bhall[blockIdx.x * NB2 + t];
        lcur[t] = c ? atomicAdd(&bcur[t], c) : 0;
    }
    __syncthreads();
    int base = blockIdx.x * CHUNKA;
    for (int i = 0; i < CHUNKA; i += 256) {
        int e = base + i + t;
        if (e < NE) {
            int d = da[e];
            int p = atomicAdd(&lcur[d >> 10], 1);
            ebuf[p] = ((unsigned)sa[e] << 10) | (unsigned)(d & 1023);
        }
    }
}

// ---- count pass: 256 thr, 4 counters/thread int4 scan -> rowptr, rs ----
__global__ __launch_bounds__(256) void k_bcount(const unsigned* __restrict__ ebuf,
                                                const int* __restrict__ bbase,
                                                int* __restrict__ rowptr,
                                                float* __restrict__ rs) {
    __shared__ int cnt[1024];
    __shared__ int scn[256];
    int b = blockIdx.x, t = threadIdx.x;
    int beg = bbase[b], end = bbase[b + 1];
    *(int4*)&cnt[t * 4] = make_int4(0, 0, 0, 0);
    __syncthreads();
    for (int i = beg + t; i < end; i += 256) atomicAdd(&cnt[ebuf[i] & 1023], 1);
    __syncthreads();
    int4 v4 = *(int4*)&cnt[t * 4];
    int s = v4.x + v4.y + v4.z + v4.w;
    scn[t] = s;
    __syncthreads();
    for (int off = 1; off < 256; off <<= 1) {
        int x = (t >= off) ? scn[t - off] : 0;
        __syncthreads();
        scn[t] += x;
        __syncthreads();
    }
    int excl = scn[t] - s;
    int p0 = beg + excl;
    int p1 = p0 + v4.x;
    int p2 = p1 + v4.y;
    int p3 = p2 + v4.z;
    int n = b * 1024 + t * 4;
    if (n + 0 < NN) { rowptr[n + 0] = p0; rs[n + 0] = rsqrtf((float)(v4.x + 1)); }
    if (n + 1 < NN) { rowptr[n + 1] = p1; rs[n + 1] = rsqrtf((float)(v4.y + 1)); }
    if (n + 2 < NN) { rowptr[n + 2] = p2; rs[n + 2] = rsqrtf((float)(v4.z + 1)); }
    if (n + 3 < NN) { rowptr[n + 3] = p3; rs[n + 3] = rsqrtf((float)(v4.w + 1)); }
}

// Swizzle for f16-pair (uint) x-tile.
#define SWZU1(n, k2) ((n) * 64 + ((k2) ^ ((((n) & 7)) << 2)))
// Swizzle for fp32 h-tile in gemm2.
#define SWZ2(n, k) ((n) * 64 + ((k) ^ ((((n) & 7)) << 2)))

// ---- FUSED: blocks 0..NB2-1 scatter col (cursors from rowptr);
//      blocks NB2.. run tiled GEMM1 (f16 dot2). ----
__global__ __launch_bounds__(256, 4) void k_scatter_gemm1(
    const unsigned* __restrict__ ebuf, const int* __restrict__ rowptr,
    const int* __restrict__ bbase, int* __restrict__ col,
    const float* __restrict__ x, const float* __restrict__ W1,
    const float* __restrict__ b1, const float* __restrict__ rs,
    ushort_t* __restrict__ xsb) {
    __shared__ unsigned xth[64 * 64];  // 16 KB (gemm1 path)
    __shared__ unsigned w1h[64 * 64];  // 16 KB (gemm1 path)
    __shared__ int cur[1024];          // 4 KB (scatter path)
    int t = threadIdx.x;

    if (blockIdx.x < NB2) {
        int b = blockIdx.x;
#pragma unroll
        for (int j = 0; j < 4; ++j) {
            int n = b * 1024 + j * 256 + t;
            cur[j * 256 + t] = (n < NN) ? rowptr[n] : 0;
        }
        int beg = bbase[b], end = bbase[b + 1];
        __syncthreads();
        for (int i = beg + t; i < end; i += 256) {
            unsigned w = ebuf[i];
            int pos = atomicAdd(&cur[w & 1023], 1);
            col[pos] = (int)(w >> 10);
        }
        return;
    }

    int base = (blockIdx.x - NB2) * 64;
#pragma unroll
    for (int i = 0; i < 8; ++i) {
        int flat = i * 1024 + t * 4;
        int node = flat >> 7, k0 = flat & 127;
        int gn = base + node;
        float4 v = make_float4(0.f, 0.f, 0.f, 0.f);
        if (gn < NN) v = *(const float4*)(x + (size_t)gn * IN_CH + k0);
        uint2 pk;
        pk.x = pkh(v.x, v.y);
        pk.y = pkh(v.z, v.w);
        *(uint2*)&xth[SWZU1(node, k0 >> 1)] = pk;
    }
#pragma unroll
    for (int i = 0; i < 16; ++i) {
        int idx = i * 256 + t;
        int k2 = idx >> 6, c = idx & 63;
        float f0 = W1[(2 * k2) * 64 + c];
        float f1 = W1[(2 * k2 + 1) * 64 + c];
        w1h[idx] = pkh(f0, f1);
    }
    __syncthreads();

    int tn = t & 15, tc = t >> 4;
    int c0 = tc * 4;
    float acc[4][4];
#pragma unroll
    for (int a = 0; a < 4; ++a)
#pragma unroll
        for (int b = 0; b < 4; ++b) acc[a][b] = 0.f;

    for (int k2 = 0; k2 < 64; k2 += 2) {
        uint2 xu[4];
#pragma unroll
        for (int jn = 0; jn < 4; ++jn)
            xu[jn] = *(uint2*)&xth[SWZU1(tn + jn * 16, k2)];
        uint4 w0 = *(uint4*)&w1h[(k2 + 0) * 64 + c0];
        uint4 w1 = *(uint4*)&w1h[(k2 + 1) * 64 + c0];
        unsigned wq0[4] = {w0.x, w0.y, w0.z, w0.w};
        unsigned wq1[4] = {w1.x, w1.y, w1.z, w1.w};
#pragma unroll
        for (int jn = 0; jn < 4; ++jn)
#pragma unroll
            for (int jc = 0; jc < 4; ++jc) {
                acc[jn][jc] = fdot2(xu[jn].x, wq0[jc], acc[jn][jc]);
                acc[jn][jc] = fdot2(xu[jn].y, wq1[jc], acc[jn][jc]);
            }
    }

    float4 bb = *(const float4*)&b1[c0];
#pragma unroll
    for (int jn = 0; jn < 4; ++jn) {
        int gn = base + tn + jn * 16;
        if (gn < NN) {
            float r = rs[gn];
            uint2 pk;
            pk.x = (unsigned)f2bf((acc[jn][0] + bb.x) * r) |
                   ((unsigned)f2bf((acc[jn][1] + bb.y) * r) << 16);
            pk.y = (unsigned)f2bf((acc[jn][2] + bb.z) * r) |
                   ((unsigned)f2bf((acc[jn][3] + bb.w) * r) << 16);
            *(uint2*)&xsb[(size_t)gn * HID_CH + c0] = pk;
        }
    }
}

// Packed accumulate of 8 bf16 channels (uint4) into 4 f32x2 via v_pk_add_f32.
#define ADD8PK(v) do { \
    f32x2 w0_, w1_, w2_, w3_; \
    w0_.x = blo((v).x); w0_.y = bhi((v).x); p0 = pk_add(p0, w0_); \
    w1_.x = blo((v).y); w1_.y = bhi((v).y); p1 = pk_add(p1, w1_); \
    w2_.x = blo((v).z); w2_.y = bhi((v).z); p2 = pk_add(p2, w2_); \
    w3_.x = blo((v).w); w3_.y = bhi((v).w); p3 = pk_add(p3, w3_); } while (0)

// ---- pull agg layer 1: wave=row, 8 groups x 8 lanes, uint4 = 8 ch ----
__global__ __launch_bounds__(256) void k_agg1(
    const int* __restrict__ rowptr, const int* __restrict__ col,
    const ushort_t* __restrict__ xsb, const float* __restrict__ rs,
    ushort_t* __restrict__ hb) {
    int gid = blockIdx.x * blockDim.x + threadIdx.x;
    int n = gid >> 6;
    if (n >= NN) return;
    int lane = threadIdx.x & 63;
    int g = lane >> 3;                       // group 0..7
    unsigned c0 = (unsigned)(lane & 7) * 8;  // channels c0..c0+7
    int beg = rowptr[n], end = rowptr[n + 1];

    f32x2 p0 = {0.f, 0.f}, p1 = {0.f, 0.f}, p2 = {0.f, 0.f}, p3 = {0.f, 0.f};
    if (g == 0) {  // self-loop
        uint4 sv = *(const uint4*)&xsb[(unsigned)n * 64u + c0];
        ADD8PK(sv);
    }

    int i = beg;
    for (; i + 16 <= end; i += 16) {  // 16 edges/iter (2 per group)
        int s0 = col[i + g];
        int s1 = col[i + 8 + g];
        uint4 v0 = *(const uint4*)&xsb[(unsigned)s0 * 64u + c0];
        uint4 v1 = *(const uint4*)&xsb[(unsigned)s1 * 64u + c0];
        ADD8PK(v0);
        ADD8PK(v1);
    }
    if (i + 8 <= end) {
        int s0 = col[i + g];
        uint4 v0 = *(const uint4*)&xsb[(unsigned)s0 * 64u + c0];
        ADD8PK(v0);
        i += 8;
    }
    int r = end - i;  // 0..7
    if (g < r) {
        int s0 = col[i + g];
        uint4 v0 = *(const uint4*)&xsb[(unsigned)s0 * 64u + c0];
        ADD8PK(v0);
    }

    float a0 = p0.x, a1 = p0.y, a2 = p1.x, a3 = p1.y;
    float a4 = p2.x, a5 = p2.y, a6 = p3.x, a7 = p3.y;
#pragma unroll
    for (int m = 8; m <= 32; m <<= 1) {
        a0 += __shfl_xor(a0, m); a1 += __shfl_xor(a1, m);
        a2 += __shfl_xor(a2, m); a3 += __shfl_xor(a3, m);
        a4 += __shfl_xor(a4, m); a5 += __shfl_xor(a5, m);
        a6 += __shfl_xor(a6, m); a7 += __shfl_xor(a7, m);
    }

    if (g == 0) {
        float rn = rs[n];
        uint4 pk;
        pk.x = (unsigned)f2bf(fmaxf(a0 * rn, 0.f)) |
               ((unsigned)f2bf(fmaxf(a1 * rn, 0.f)) << 16);
        pk.y = (unsigned)f2bf(fmaxf(a2 * rn, 0.f)) |
               ((unsigned)f2bf(fmaxf(a3 * rn, 0.f)) << 16);
        pk.z = (unsigned)f2bf(fmaxf(a4 * rn, 0.f)) |
               ((unsigned)f2bf(fmaxf(a5 * rn, 0.f)) << 16);
        pk.w = (unsigned)f2bf(fmaxf(a6 * rn, 0.f)) |
               ((unsigned)f2bf(fmaxf(a7 * rn, 0.f)) << 16);
        *(uint4*)&hb[(unsigned)n * 64u + c0] = pk;
    }
}

// ---- tiled GEMM2: ysb[n][c] = bf16(((h[n] @ W2 + b2)[c]) * rs[n]) ----
__global__ __launch_bounds__(256) void k_gemm2(
    const ushort_t* __restrict__ hb, const float* __restrict__ W2,
    const float* __restrict__ b2, const float* __restrict__ rs,
    ushort_t* __restrict__ ysb) {
    __shared__ float ht[64 * 64];   // 16 KB, swizzled fp32
    __shared__ float w2s[64 * 32];  // 8 KB
    int t = threadIdx.x;
    int base = blockIdx.x * 64;

#pragma unroll
    for (int i = 0; i < 8; ++i) {
        int uidx = i * 256 + t;            // 2048 uints total
        int node = uidx >> 5, k2 = uidx & 31;
        int gn = base + node;
        unsigned u = 0;
        if (gn < NN) u = *(const unsigned*)&hb[(size_t)gn * HID_CH + k2 * 2];
        float2 f; f.x = blo(u); f.y = bhi(u);
        *(float2*)&ht[SWZ2(node, k2 * 2)] = f;
    }
#pragma unroll
    for (int i = 0; i < 2; ++i) {
        int flat = i * 1024 + t * 4;
        *(float4*)&w2s[flat] = *(const float4*)(W2 + flat);
    }
    __syncthreads();

    int tn = t & 15, tc = t >> 4;
    int c0 = tc * 2;
    float acc[4][2];
#pragma unroll
    for (int a = 0; a < 4; ++a) { acc[a][0] = 0.f; acc[a][1] = 0.f; }

    for (int k0 = 0; k0 < 64; k0 += 4) {
        float xq[4][4], wq[4][2];
#pragma unroll
        for (int j = 0; j < 4; ++j)
            *(float2*)&wq[j][0] = *(float2*)&w2s[(k0 + j) * 32 + c0];
#pragma unroll
        for (int jn = 0; jn < 4; ++jn)
            *(float4*)&xq[jn][0] = *(float4*)&ht[SWZ2(tn + jn * 16, k0)];
#pragma unroll
        for (int jn = 0; jn < 4; ++jn)
#pragma unroll
            for (int j = 0; j < 4; ++j) {
                acc[jn][0] = fmaf(xq[jn][j], wq[j][0], acc[jn][0]);
                acc[jn][1] = fmaf(xq[jn][j], wq[j][1], acc[jn][1]);
            }
    }

    float2 bb = *(const float2*)&b2[c0];
#pragma unroll
    for (int jn = 0; jn < 4; ++jn) {
        int gn = base + tn + jn * 16;
        if (gn < NN) {
            float r = rs[gn];
            unsigned pk = (unsigned)f2bf((acc[jn][0] + bb.x) * r) |
                          ((unsigned)f2bf((acc[jn][1] + bb.y) * r) << 16);
            *(unsigned*)&ysb[(size_t)gn * OUT_CH + c0] = pk;
        }
    }
}

// ---- pull agg layer 2: wave=row, 16 groups x 4 lanes, uint4 = 8 ch ----
__global__ __launch_bounds__(256) void k_agg2(
    const int* __restrict__ rowptr, const int* __restrict__ col,
    const ushort_t* __restrict__ ysb, const float* __restrict__ rs,
    float* __restrict__ out) {
    int gid = blockIdx.x * blockDim.x + threadIdx.x;
    int n = gid >> 6;
    if (n >= NN) return;
    int lane = threadIdx.x & 63;
    int g = lane >> 2;                       // group 0..15
    unsigned c0 = (unsigned)(lane & 3) * 8;  // channels c0..c0+7
    int beg = rowptr[n], end = rowptr[n + 1];

    f32x2 p0 = {0.f, 0.f}, p1 = {0.f, 0.f}, p2 = {0.f, 0.f}, p3 = {0.f, 0.f};
    if (g == 0) {  // self-loop
        uint4 sv = *(const uint4*)&ysb[(unsigned)n * 32u + c0];
        ADD8PK(sv);
    }

    int i = beg;
    for (; i + 16 <= end; i += 16) {  // 16 edges/iter (1 per group)
        int s0 = col[i + g];
        uint4 v0 = *(const uint4*)&ysb[(unsigned)s0 * 32u + c0];
        ADD8PK(v0);
    }
    int r = end - i;  // 0..15
    if (g < r) {
        int s0 = col[i + g];
        uint4 v0 = *(const uint4*)&ysb[(unsigned)s0 * 32u + c0];
        ADD8PK(v0);
    }

    float a0 = p0.x, a1 = p0.y, a2 = p1.x, a3 = p1.y;
    float a4 = p2.x, a5 = p2.y, a6 = p3.x, a7 = p3.y;
#pragma unroll
    for (int m = 4; m <= 32; m <<= 1) {
        a0 += __shfl_xor(a0, m); a1 += __shfl_xor(a1, m);
        a2 += __shfl_xor(a2, m); a3 += __shfl_xor(a3, m);
        a4 += __shfl_xor(a4, m); a5 += __shfl_xor(a5, m);
        a6 += __shfl_xor(a6, m); a7 += __shfl_xor(a7, m);
    }

    if (g == 0) {
        float rn = rs[n];
        float4 o0, o1;
        o0.x = a0 * rn; o0.y = a1 * rn; o0.z = a2 * rn; o0.w = a3 * rn;
        o1.x = a4 * rn; o1.y = a5 * rn; o1.z = a6 * rn; o1.w = a7 * rn;
        *(float4*)&out[(size_t)n * OUT_CH + c0] = o0;
        *(float4*)&out[(size_t)n * OUT_CH + c0 + 4] = o1;
    }
}

extern "C" void kernel_launch(void* const* d_in, const int* in_sizes, int n_in,
                              void* d_out, int out_size, void* d_ws, size_t ws_size,
                              hipStream_t stream) {
    const float* x  = (const float*)d_in[0];
    const int*   ei = (const int*)d_in[1];  // (2, E): row 0 = src, row 1 = dst
    const float* W1 = (const float*)d_in[2];
    const float* b1 = (const float*)d_in[3];
    const float* W2 = (const float*)d_in[4];
    const float* b2 = (const float*)d_in[5];
    const int* sa = ei;
    const int* da = ei + NE;

    char* ws = (char*)d_ws;
    size_t off = 0;
    auto alloc = [&](size_t bytes) {
        void* p = ws + off;
        off += (bytes + 255) & ~(size_t)255;
        return p;
    };
    int*      bbase  = (int*)alloc((size_t)(NB2 + 1) * 4);
    int*      bcur   = (int*)alloc((size_t)NB2 * 4);
    int*      bhall  = (int*)alloc((size_t)NBLKA * NB2 * 4);  // 77 KB
    int*      rowptr = (int*)alloc((size_t)(NN + 1) * 4);
    float*    rs     = (float*)alloc((size_t)NN * 4);
    unsigned* ebuf   = (unsigned*)alloc((size_t)NE * 4);
    int*      col    = (int*)alloc((size_t)NE * 4);
    ushort_t* xsb    = (ushort_t*)alloc((size_t)NN * HID_CH * 2);  // 12.8 MB
    ushort_t* hb     = (ushort_t*)alloc((size_t)NN * HID_CH * 2);  // 12.8 MB
    ushort_t* ysb    = (ushort_t*)alloc((size_t)NN * OUT_CH * 2);  // 6.4 MB
    float*    outp   = (float*)d_out;

    const int B = 256;
    k_bhist<<<NBLKA, 256, 0, stream>>>(da, bhall);
    k_bscan<<<1, 128, 0, stream>>>(bhall, bbase, bcur, rowptr);
    k_bfill<<<NBLKA, 256, 0, stream>>>(sa, da, bhall, bcur, ebuf);
    k_bcount<<<NB2, 256, 0, stream>>>(ebuf, bbase, rowptr, rs);
    k_scatter_gemm1<<<NB2 + NBLK_GEMM, 256, 0, stream>>>(ebuf, rowptr, bbase, col,
                                                         x, W1, b1, rs, xsb);
    k_agg1<<<(NN * 64 + B - 1) / B, B, 0, stream>>>(rowptr, col, xsb, rs, hb);
    k_gemm2<<<NBLK_GEMM, 256, 0, stream>>>(hb, W2, b2, rs, ysb);
    k_agg2<<<(NN * 64 + B - 1) / B, B, 0, stream>>>(rowptr, col, ysb, rs, outp);
}

// Round 20
// 209.975 us; speedup vs baseline: 2.1074x; 1.0375x over previous
//
#include <hip/hip_runtime.h>

#define NN 100000
#define NE 1600000
#define IN_CH 128
#define HID_CH 64
#define OUT_CH 32
#define NB2 98               // ceil(NN/1024) coarse buckets of 1024 nodes
#define CHUNKA 8192          // edges per block in bucket passes
#define NBLKA ((NE + CHUNKA - 1) / CHUNKA)   // 196
#define NBLK_GEMM ((NN + 63) / 64)           // 1563

typedef unsigned short ushort_t;
typedef _Float16 half2_t __attribute__((ext_vector_type(2)));
typedef float f32x2 __attribute__((ext_vector_type(2)));

__device__ inline ushort_t f2bf(float f) {  // round-to-nearest-even
    union { float f; unsigned u; } v; v.f = f;
    unsigned r = v.u + 0x7fff + ((v.u >> 16) & 1);
    return (ushort_t)(r >> 16);
}
__device__ inline float blo(unsigned u) {
    union { unsigned x; float f; } v; v.x = u << 16; return v.f;
}
__device__ inline float bhi(unsigned u) {
    union { unsigned x; float f; } v; v.x = u & 0xffff0000u; return v.f;
}
__device__ inline unsigned pkh(float a, float b) {  // pack 2 f32 -> f16x2
    union { half2_t h; unsigned u; } v;
    v.h[0] = (_Float16)a; v.h[1] = (_Float16)b;
    return v.u;
}
__device__ inline half2_t u2h(unsigned u) {
    union { unsigned u; half2_t h; } v; v.u = u; return v.h;
}
__device__ inline float fdot2(unsigned a, unsigned b, float c) {
#if __has_builtin(__builtin_amdgcn_fdot2)
    return __builtin_amdgcn_fdot2(u2h(a), u2h(b), c, false);
#else
    half2_t ha = u2h(a), hb = u2h(b);
    return c + (float)ha[0] * (float)hb[0] + (float)ha[1] * (float)hb[1];
#endif
}
__device__ inline f32x2 pk_add(f32x2 a, f32x2 b) {  // v_pk_add_f32 (CDNA2+)
    f32x2 r;
    asm("v_pk_add_f32 %0, %1, %2" : "=v"(r) : "v"(a), "v"(b));
    return r;
}

// ---- coarse bucket histogram (dst>>10); persists per-block rows ----
__global__ __launch_bounds__(256) void k_bhist(const int* __restrict__ da,
                                               int* __restrict__ bcnt,
                                               int* __restrict__ bhall) {
    __shared__ int hist[4][NB2];
    int t = threadIdx.x, w = t >> 6;
    for (int i = t; i < 4 * NB2; i += 256) ((int*)hist)[i] = 0;
    __syncthreads();
    int base = blockIdx.x * CHUNKA;
    for (int i = 0; i < CHUNKA; i += 256) {
        int e = base + i + t;
        if (e < NE) atomicAdd(&hist[w][da[e] >> 10], 1);
    }
    __syncthreads();
    if (t < NB2) {
        int c = hist[0][t] + hist[1][t] + hist[2][t] + hist[3][t];
        bhall[blockIdx.x * NB2 + t] = c;
        if (c) atomicAdd(&bcnt[t], c);
    }
}

// ---- scan bucket counts -> bucket bases & cursors (one block) ----
__global__ __launch_bounds__(128) void k_bscan(const int* __restrict__ bcnt,
                                               int* __restrict__ bbase,
                                               int* __restrict__ bcur,
                                               int* __restrict__ rowptr) {
    __shared__ int lds[128];
    int t = threadIdx.x;
    int v = (t < NB2) ? bcnt[t] : 0;
    lds[t] = v;
    __syncthreads();
    for (int off = 1; off < 128; off <<= 1) {
        int x = (t >= off) ? lds[t - off] : 0;
        __syncthreads();
        lds[t] += x;
        __syncthreads();
    }
    int excl = lds[t] - v;
    if (t < NB2) { bbase[t] = excl; bcur[t] = excl; }
    if (t == 0) { bbase[NB2] = NE; rowptr[NN] = NE; }
}

// ---- bucket fill: reuses bhist's stored counts (no recount pass) ----
__global__ __launch_bounds__(256) void k_bfill(const int* __restrict__ sa,
                                               const int* __restrict__ da,
                                               const int* __restrict__ bhall,
                                               int* __restrict__ bcur,
                                               unsigned* __restrict__ ebuf) {
    __shared__ int lcur[NB2];
    int t = threadIdx.x;
    if (t < NB2) {
        int c = bhall[blockIdx.x * NB2 + t];
        lcur[t] = c ? atomicAdd(&bcur[t], c) : 0;
    }
    __syncthreads();
    int base = blockIdx.x * CHUNKA;
    for (int i = 0; i < CHUNKA; i += 256) {
        int e = base + i + t;
        if (e < NE) {
            int d = da[e];
            int p = atomicAdd(&lcur[d >> 10], 1);
            ebuf[p] = ((unsigned)sa[e] << 10) | (unsigned)(d & 1023);
        }
    }
}

// ---- count pass: per-bucket node counts -> rowptr, rs (NO scatter) ----
__global__ __launch_bounds__(1024) void k_bcount(const unsigned* __restrict__ ebuf,
                                                 const int* __restrict__ bbase,
                                                 int* __restrict__ rowptr,
                                                 float* __restrict__ rs) {
    __shared__ int cnt[1024];
    __shared__ int scn[1024];
    int b = blockIdx.x, t = threadIdx.x;
    int nb = NN - b * 1024; if (nb > 1024) nb = 1024;
    int beg = bbase[b], end = bbase[b + 1];
    cnt[t] = 0;
    __syncthreads();
    for (int i = beg + t; i < end; i += 1024) atomicAdd(&cnt[ebuf[i] & 1023], 1);
    __syncthreads();
    int v = cnt[t];
    scn[t] = v;
    __syncthreads();
    for (int off = 1; off < 1024; off <<= 1) {
        int x = (t >= off) ? scn[t - off] : 0;
        __syncthreads();
        scn[t] += x;
        __syncthreads();
    }
    int excl = scn[t] - v;
    if (t < nb) {
        rowptr[b * 1024 + t] = beg + excl;
        rs[b * 1024 + t] = rsqrtf((float)(v + 1));
    }
}

// Swizzle for f16-pair (uint) x-tile.
#define SWZU1(n, k2) ((n) * 64 + ((k2) ^ ((((n) & 7)) << 2)))
// Swizzle for fp32 h-tile in gemm2.
#define SWZ2(n, k) ((n) * 64 + ((k) ^ ((((n) & 7)) << 2)))

// ---- FUSED: blocks 0..NB2-1 scatter col (cursors from rowptr);
//      blocks NB2.. run tiled GEMM1 (f16 dot2). ----
__global__ __launch_bounds__(256, 4) void k_scatter_gemm1(
    const unsigned* __restrict__ ebuf, const int* __restrict__ rowptr,
    const int* __restrict__ bbase, int* __restrict__ col,
    const float* __restrict__ x, const float* __restrict__ W1,
    const float* __restrict__ b1, const float* __restrict__ rs,
    ushort_t* __restrict__ xsb) {
    __shared__ unsigned xth[64 * 64];  // 16 KB (gemm1 path)
    __shared__ unsigned w1h[64 * 64];  // 16 KB (gemm1 path)
    __shared__ int cur[1024];          // 4 KB (scatter path)
    int t = threadIdx.x;

    if (blockIdx.x < NB2) {
        int b = blockIdx.x;
#pragma unroll
        for (int j = 0; j < 4; ++j) {
            int n = b * 1024 + j * 256 + t;
            cur[j * 256 + t] = (n < NN) ? rowptr[n] : 0;
        }
        int beg = bbase[b], end = bbase[b + 1];
        __syncthreads();
        for (int i = beg + t; i < end; i += 256) {
            unsigned w = ebuf[i];
            int pos = atomicAdd(&cur[w & 1023], 1);
            col[pos] = (int)(w >> 10);
        }
        return;
    }

    int base = (blockIdx.x - NB2) * 64;
#pragma unroll
    for (int i = 0; i < 8; ++i) {
        int flat = i * 1024 + t * 4;
        int node = flat >> 7, k0 = flat & 127;
        int gn = base + node;
        float4 v = make_float4(0.f, 0.f, 0.f, 0.f);
        if (gn < NN) v = *(const float4*)(x + (size_t)gn * IN_CH + k0);
        uint2 pk;
        pk.x = pkh(v.x, v.y);
        pk.y = pkh(v.z, v.w);
        *(uint2*)&xth[SWZU1(node, k0 >> 1)] = pk;
    }
#pragma unroll
    for (int i = 0; i < 16; ++i) {
        int idx = i * 256 + t;
        int k2 = idx >> 6, c = idx & 63;
        float f0 = W1[(2 * k2) * 64 + c];
        float f1 = W1[(2 * k2 + 1) * 64 + c];
        w1h[idx] = pkh(f0, f1);
    }
    __syncthreads();

    int tn = t & 15, tc = t >> 4;
    int c0 = tc * 4;
    float acc[4][4];
#pragma unroll
    for (int a = 0; a < 4; ++a)
#pragma unroll
        for (int b = 0; b < 4; ++b) acc[a][b] = 0.f;

    for (int k2 = 0; k2 < 64; k2 += 2) {
        uint2 xu[4];
#pragma unroll
        for (int jn = 0; jn < 4; ++jn)
            xu[jn] = *(uint2*)&xth[SWZU1(tn + jn * 16, k2)];
        uint4 w0 = *(uint4*)&w1h[(k2 + 0) * 64 + c0];
        uint4 w1 = *(uint4*)&w1h[(k2 + 1) * 64 + c0];
        unsigned wq0[4] = {w0.x, w0.y, w0.z, w0.w};
        unsigned wq1[4] = {w1.x, w1.y, w1.z, w1.w};
#pragma unroll
        for (int jn = 0; jn < 4; ++jn)
#pragma unroll
            for (int jc = 0; jc < 4; ++jc) {
                acc[jn][jc] = fdot2(xu[jn].x, wq0[jc], acc[jn][jc]);
                acc[jn][jc] = fdot2(xu[jn].y, wq1[jc], acc[jn][jc]);
            }
    }

    float4 bb = *(const float4*)&b1[c0];
#pragma unroll
    for (int jn = 0; jn < 4; ++jn) {
        int gn = base + tn + jn * 16;
        if (gn < NN) {
            float r = rs[gn];
            uint2 pk;
            pk.x = (unsigned)f2bf((acc[jn][0] + bb.x) * r) |
                   ((unsigned)f2bf((acc[jn][1] + bb.y) * r) << 16);
            pk.y = (unsigned)f2bf((acc[jn][2] + bb.z) * r) |
                   ((unsigned)f2bf((acc[jn][3] + bb.w) * r) << 16);
            *(uint2*)&xsb[(size_t)gn * HID_CH + c0] = pk;
        }
    }
}

// Packed accumulate of 8 bf16 channels (uint4) into 4 f32x2 via v_pk_add_f32.
#define ADD8PK(v) do { \
    f32x2 w0_, w1_, w2_, w3_; \
    w0_.x = blo((v).x); w0_.y = bhi((v).x); p0 = pk_add(p0, w0_); \
    w1_.x = blo((v).y); w1_.y = bhi((v).y); p1 = pk_add(p1, w1_); \
    w2_.x = blo((v).z); w2_.y = bhi((v).z); p2 = pk_add(p2, w2_); \
    w3_.x = blo((v).w); w3_.y = bhi((v).w); p3 = pk_add(p3, w3_); } while (0)

// ---- pull agg layer 1: wave=row, 8 groups x 8 lanes, uint4 = 8 ch ----
__global__ __launch_bounds__(256) void k_agg1(
    const int* __restrict__ rowptr, const int* __restrict__ col,
    const ushort_t* __restrict__ xsb, const float* __restrict__ rs,
    ushort_t* __restrict__ hb) {
    int gid = blockIdx.x * blockDim.x + threadIdx.x;
    int n = gid >> 6;
    if (n >= NN) return;
    int lane = threadIdx.x & 63;
    int g = lane >> 3;                       // group 0..7
    unsigned c0 = (unsigned)(lane & 7) * 8;  // channels c0..c0+7
    int beg = rowptr[n], end = rowptr[n + 1];

    f32x2 p0 = {0.f, 0.f}, p1 = {0.f, 0.f}, p2 = {0.f, 0.f}, p3 = {0.f, 0.f};
    if (g == 0) {  // self-loop
        uint4 sv = *(const uint4*)&xsb[(unsigned)n * 64u + c0];
        ADD8PK(sv);
    }

    int i = beg;
    for (; i + 16 <= end; i += 16) {  // 16 edges/iter (2 per group)
        int s0 = col[i + g];
        int s1 = col[i + 8 + g];
        uint4 v0 = *(const uint4*)&xsb[(unsigned)s0 * 64u + c0];
        uint4 v1 = *(const uint4*)&xsb[(unsigned)s1 * 64u + c0];
        ADD8PK(v0);
        ADD8PK(v1);
    }
    if (i + 8 <= end) {
        int s0 = col[i + g];
        uint4 v0 = *(const uint4*)&xsb[(unsigned)s0 * 64u + c0];
        ADD8PK(v0);
        i += 8;
    }
    int r = end - i;  // 0..7
    if (g < r) {
        int s0 = col[i + g];
        uint4 v0 = *(const uint4*)&xsb[(unsigned)s0 * 64u + c0];
        ADD8PK(v0);
    }

    float a0 = p0.x, a1 = p0.y, a2 = p1.x, a3 = p1.y;
    float a4 = p2.x, a5 = p2.y, a6 = p3.x, a7 = p3.y;
#pragma unroll
    for (int m = 8; m <= 32; m <<= 1) {
        a0 += __shfl_xor(a0, m); a1 += __shfl_xor(a1, m);
        a2 += __shfl_xor(a2, m); a3 += __shfl_xor(a3, m);
        a4 += __shfl_xor(a4, m); a5 += __shfl_xor(a5, m);
        a6 += __shfl_xor(a6, m); a7 += __shfl_xor(a7, m);
    }

    if (g == 0) {
        float rn = rs[n];
        uint4 pk;
        pk.x = (unsigned)f2bf(fmaxf(a0 * rn, 0.f)) |
               ((unsigned)f2bf(fmaxf(a1 * rn, 0.f)) << 16);
        pk.y = (unsigned)f2bf(fmaxf(a2 * rn, 0.f)) |
               ((unsigned)f2bf(fmaxf(a3 * rn, 0.f)) << 16);
        pk.z = (unsigned)f2bf(fmaxf(a4 * rn, 0.f)) |
               ((unsigned)f2bf(fmaxf(a5 * rn, 0.f)) << 16);
        pk.w = (unsigned)f2bf(fmaxf(a6 * rn, 0.f)) |
               ((unsigned)f2bf(fmaxf(a7 * rn, 0.f)) << 16);
        *(uint4*)&hb[(unsigned)n * 64u + c0] = pk;
    }
}

// ---- tiled GEMM2: ysb[n][c] = bf16(((h[n] @ W2 + b2)[c]) * rs[n]) ----
__global__ __launch_bounds__(256) void k_gemm2(
    const ushort_t* __restrict__ hb, const float* __restrict__ W2,
    const float* __restrict__ b2, const float* __restrict__ rs,
    ushort_t* __restrict__ ysb) {
    __shared__ float ht[64 * 64];   // 16 KB, swizzled fp32
    __shared__ float w2s[64 * 32];  // 8 KB
    int t = threadIdx.x;
    int base = blockIdx.x * 64;

#pragma unroll
    for (int i = 0; i < 8; ++i) {
        int uidx = i * 256 + t;            // 2048 uints total
        int node = uidx >> 5, k2 = uidx & 31;
        int gn = base + node;
        unsigned u = 0;
        if (gn < NN) u = *(const unsigned*)&hb[(size_t)gn * HID_CH + k2 * 2];
        float2 f; f.x = blo(u); f.y = bhi(u);
        *(float2*)&ht[SWZ2(node, k2 * 2)] = f;
    }
#pragma unroll
    for (int i = 0; i < 2; ++i) {
        int flat = i * 1024 + t * 4;
        *(float4*)&w2s[flat] = *(const float4*)(W2 + flat);
    }
    __syncthreads();

    int tn = t & 15, tc = t >> 4;
    int c0 = tc * 2;
    float acc[4][2];
#pragma unroll
    for (int a = 0; a < 4; ++a) { acc[a][0] = 0.f; acc[a][1] = 0.f; }

    for (int k0 = 0; k0 < 64; k0 += 4) {
        float xq[4][4], wq[4][2];
#pragma unroll
        for (int j = 0; j < 4; ++j)
            *(float2*)&wq[j][0] = *(float2*)&w2s[(k0 + j) * 32 + c0];
#pragma unroll
        for (int jn = 0; jn < 4; ++jn)
            *(float4*)&xq[jn][0] = *(float4*)&ht[SWZ2(tn + jn * 16, k0)];
#pragma unroll
        for (int jn = 0; jn < 4; ++jn)
#pragma unroll
            for (int j = 0; j < 4; ++j) {
                acc[jn][0] = fmaf(xq[jn][j], wq[j][0], acc[jn][0]);
                acc[jn][1] = fmaf(xq[jn][j], wq[j][1], acc[jn][1]);
            }
    }

    float2 bb = *(const float2*)&b2[c0];
#pragma unroll
    for (int jn = 0; jn < 4; ++jn) {
        int gn = base + tn + jn * 16;
        if (gn < NN) {
            float r = rs[gn];
            unsigned pk = (unsigned)f2bf((acc[jn][0] + bb.x) * r) |
                          ((unsigned)f2bf((acc[jn][1] + bb.y) * r) << 16);
            *(unsigned*)&ysb[(size_t)gn * OUT_CH + c0] = pk;
        }
    }
}

// ---- pull agg layer 2: wave=row, 16 groups x 4 lanes, uint4 = 8 ch ----
__global__ __launch_bounds__(256) void k_agg2(
    const int* __restrict__ rowptr, const int* __restrict__ col,
    const ushort_t* __restrict__ ysb, const float* __restrict__ rs,
    float* __restrict__ out) {
    int gid = blockIdx.x * blockDim.x + threadIdx.x;
    int n = gid >> 6;
    if (n >= NN) return;
    int lane = threadIdx.x & 63;
    int g = lane >> 2;                       // group 0..15
    unsigned c0 = (unsigned)(lane & 3) * 8;  // channels c0..c0+7
    int beg = rowptr[n], end = rowptr[n + 1];

    f32x2 p0 = {0.f, 0.f}, p1 = {0.f, 0.f}, p2 = {0.f, 0.f}, p3 = {0.f, 0.f};
    if (g == 0) {  // self-loop
        uint4 sv = *(const uint4*)&ysb[(unsigned)n * 32u + c0];
        ADD8PK(sv);
    }

    int i = beg;
    for (; i + 16 <= end; i += 16) {  // 16 edges/iter (1 per group)
        int s0 = col[i + g];
        uint4 v0 = *(const uint4*)&ysb[(unsigned)s0 * 32u + c0];
        ADD8PK(v0);
    }
    int r = end - i;  // 0..15
    if (g < r) {
        int s0 = col[i + g];
        uint4 v0 = *(const uint4*)&ysb[(unsigned)s0 * 32u + c0];
        ADD8PK(v0);
    }

    float a0 = p0.x, a1 = p0.y, a2 = p1.x, a3 = p1.y;
    float a4 = p2.x, a5 = p2.y, a6 = p3.x, a7 = p3.y;
#pragma unroll
    for (int m = 4; m <= 32; m <<= 1) {
        a0 += __shfl_xor(a0, m); a1 += __shfl_xor(a1, m);
        a2 += __shfl_xor(a2, m); a3 += __shfl_xor(a3, m);
        a4 += __shfl_xor(a4, m); a5 += __shfl_xor(a5, m);
        a6 += __shfl_xor(a6, m); a7 += __shfl_xor(a7, m);
    }

    if (g == 0) {
        float rn = rs[n];
        float4 o0, o1;
        o0.x = a0 * rn; o0.y = a1 * rn; o0.z = a2 * rn; o0.w = a3 * rn;
        o1.x = a4 * rn; o1.y = a5 * rn; o1.z = a6 * rn; o1.w = a7 * rn;
        *(float4*)&out[(size_t)n * OUT_CH + c0] = o0;
        *(float4*)&out[(size_t)n * OUT_CH + c0 + 4] = o1;
    }
}

extern "C" void kernel_launch(void* const* d_in, const int* in_sizes, int n_in,
                              void* d_out, int out_size, void* d_ws, size_t ws_size,
                              hipStream_t stream) {
    const float* x  = (const float*)d_in[0];
    const int*   ei = (const int*)d_in[1];  // (2, E): row 0 = src, row 1 = dst
    const float* W1 = (const float*)d_in[2];
    const float* b1 = (const float*)d_in[3];
    const float* W2 = (const float*)d_in[4];
    const float* b2 = (const float*)d_in[5];
    const int* sa = ei;
    const int* da = ei + NE;

    char* ws = (char*)d_ws;
    size_t off = 0;
    auto alloc = [&](size_t bytes) {
        void* p = ws + off;
        off += (bytes + 255) & ~(size_t)255;
        return p;
    };
    int*      bcnt   = (int*)alloc((size_t)NB2 * 4);
    int*      bbase  = (int*)alloc((size_t)(NB2 + 1) * 4);
    int*      bcur   = (int*)alloc((size_t)NB2 * 4);
    int*      bhall  = (int*)alloc((size_t)NBLKA * NB2 * 4);  // 77 KB
    int*      rowptr = (int*)alloc((size_t)(NN + 1) * 4);
    float*    rs     = (float*)alloc((size_t)NN * 4);
    unsigned* ebuf   = (unsigned*)alloc((size_t)NE * 4);
    int*      col    = (int*)alloc((size_t)NE * 4);
    ushort_t* xsb    = (ushort_t*)alloc((size_t)NN * HID_CH * 2);  // 12.8 MB
    ushort_t* hb     = (ushort_t*)alloc((size_t)NN * HID_CH * 2);  // 12.8 MB
    ushort_t* ysb    = (ushort_t*)alloc((size_t)NN * OUT_CH * 2);  // 6.4 MB
    float*    outp   = (float*)d_out;

    const int B = 256;
    hipMemsetAsync(bcnt, 0, (size_t)NB2 * 4, stream);
    k_bhist<<<NBLKA, 256, 0, stream>>>(da, bcnt, bhall);
    k_bscan<<<1, 128, 0, stream>>>(bcnt, bbase, bcur, rowptr);
    k_bfill<<<NBLKA, 256, 0, stream>>>(sa, da, bhall, bcur, ebuf);
    k_bcount<<<NB2, 1024, 0, stream>>>(ebuf, bbase, rowptr, rs);
    k_scatter_gemm1<<<NB2 + NBLK_GEMM, 256, 0, stream>>>(ebuf, rowptr, bbase, col,
                                                         x, W1, b1, rs, xsb);
    k_agg1<<<(NN * 64 + B - 1) / B, B, 0, stream>>>(rowptr, col, xsb, rs, hb);
    k_gemm2<<<NBLK_GEMM, 256, 0, stream>>>(hb, W2, b2, rs, ysb);
    k_agg2<<<(NN * 64 + B - 1) / B, B, 0, stream>>>(rowptr, col, ysb, rs, outp);
}